// Round 6
// baseline (1321.343 us; speedup 1.0000x reference)
//
#include <hip/hip_runtime.h>
#include <math.h>

// Model constants
static constexpr int Bc = 64;
static constexpr int Kc = 1024;
static constexpr int Cc = 512;
static constexpr int Dc = 256;
static constexpr int Hc = 4;
static constexpr int Sc = 1026;       // 2 + K
static constexpr int FFc = 1024;
static constexpr float EPSc = 1e-5f;
static constexpr float SCALEc = 0.125f;   // 1/sqrt(64)
static constexpr float NEG_OUT = -1.0e30f;  // finite stand-in for -inf (see R1)

typedef __attribute__((ext_vector_type(8))) short short8;
typedef __attribute__((ext_vector_type(8))) unsigned short u16x8;
typedef __attribute__((ext_vector_type(4))) float f32x4;

__device__ __forceinline__ float bf2f(unsigned short u) {
  union { float f; unsigned int i; } c; c.i = ((unsigned int)u) << 16; return c.f;
}
__device__ __forceinline__ unsigned short f2bf(float f) {
  union { float f; unsigned int i; } c; c.f = f;
  unsigned int i = c.i;
  unsigned int r = (i + 0x7fffu + ((i >> 16) & 1u)) >> 16;  // RNE
  return (unsigned short)r;
}

__device__ __forceinline__ float wave_sum(float v) {
#pragma unroll
  for (int off = 32; off > 0; off >>= 1) v += __shfl_xor(v, off, 64);
  return v;
}
__device__ __forceinline__ float wave_max(float v) {
#pragma unroll
  for (int off = 32; off > 0; off >>= 1) v = fmaxf(v, __shfl_xor(v, off, 64));
  return v;
}

__device__ __forceinline__ void async_ld16(const unsigned short* g, unsigned short* l) {
  __builtin_amdgcn_global_load_lds(
      (const __attribute__((address_space(1))) void*)g,
      (__attribute__((address_space(3))) void*)l, 16, 0, 0);
}

// Fast GELU: tanh-form, err ~1e-3 relative (below bf16 rounding).
__device__ __forceinline__ float gelu_fast(float u) {
  const float z = 1.5957691216057308f * u * (1.0f + 0.044715f * u * u);
  return u / (1.0f + __expf(-z));
}

// ---------------------------------------------------------------------------
// bf16 MFMA GEMM, BK=64, DOUBLE-BUFFERED LDS, one barrier per iter.
// Loop: sync (drains loads issued one iter ago) -> issue prefetch into other
// buffer -> ds_read+MFMA current buffer (2 K=32 substeps).
// A: [M][Kd] bf16 (CASTA=0) or fp32 (CASTA=1, cast fused into LDS staging).
// W: [N][Kd] bf16 row-major.
// EPI: 1 = +extraF[n] (type-emb); 2 = +bf16 extraB[orow*ldc+n] (residual,
//      in-place OK); 3 = fast GELU; 4 = bias only.  All outputs bf16.
// MAP: 1 = candidate row scatter m -> (m>>10)*1026+2+(m&1023).
// Tile 128x128, 256 threads = 4 waves, wave 64x64 = 4x4 16x16x32 MFMA.
// 8-chunk XOR swizzle (R4-verified: 0 bank conflicts). LDS 64 KB.
// ---------------------------------------------------------------------------
template <int EPI, int MAP, int CASTA>
__global__ __launch_bounds__(256) void gemm_mfma(
    const void* __restrict__ Av, const unsigned short* __restrict__ W,
    const float* __restrict__ bias, const void* extra,
    void* Cout, int N, int Kd, int ldc) {
  __shared__ unsigned short As[2][8192];  // [128 rows][64 k] = 16 KB per buf
  __shared__ unsigned short Ws[2][8192];
  const int tid = threadIdx.x;
  const int w = tid >> 6;
  const int lane = tid & 63;
  const int m0 = blockIdx.x * 128;
  const int n0 = blockIdx.y * 128;

  const unsigned short* A = (const unsigned short*)Av;
  const float* Af = (const float*)Av;

  // Staging: wave w, call c (0..3) covers rows [(w*4+c)*8, +8); 8 lanes/row,
  // 16 B each. Phys chunk = lane&7, global chunk XOR row&7 (bank swizzle).
  const unsigned short* pA[4];
  const unsigned short* pB[4];
  int lofs[4];
#pragma unroll
  for (int c = 0; c < 4; ++c) {
    const int sr = (w * 4 + c) * 8 + (lane >> 3);
    const int kc = ((lane & 7) ^ (sr & 7)) * 8;
    if (!CASTA) pA[c] = A + (size_t)(m0 + sr) * Kd + kc;
    pB[c] = W + (size_t)(n0 + sr) * Kd + kc;
    lofs[c] = (w * 4 + c) * 512;  // 512 shorts = 8 rows x 128 B
  }

  f32x4 zero = {0.f, 0.f, 0.f, 0.f};
  f32x4 acc[4][4];
#pragma unroll
  for (int i = 0; i < 4; ++i)
#pragma unroll
    for (int j = 0; j < 4; ++j) acc[i][j] = zero;

  const int mrow = (w & 1) * 64;
  const int nrow = (w >> 1) * 64;
  const int l15 = lane & 15;
  const int quad = lane >> 4;

  auto stage = [&](int kk, int b) {
    if (CASTA) {
      // fp32 A -> bf16 LDS: 8 x (float4 load, cvt, 8B ds_write), swizzled
      // like the async path (chunk XOR row&7).
#pragma unroll
      for (int wi = 0; wi < 8; ++wi) {
        const int g = wi * 256 + tid;     // 0..2047
        const int row = g >> 4;           // 16 float4-groups per 64-k row
        const int k4 = g & 15;
        const int phys = row * 64 + (((k4 >> 1) ^ (row & 7)) << 3) + ((k4 & 1) << 2);
        const float4 a4 =
            *(const float4*)(Af + (size_t)(m0 + row) * Kd + kk + k4 * 4);
        ushort4 o;
        o.x = f2bf(a4.x); o.y = f2bf(a4.y); o.z = f2bf(a4.z); o.w = f2bf(a4.w);
        *(ushort4*)(&As[b][phys]) = o;
      }
    } else {
#pragma unroll
      for (int c = 0; c < 4; ++c) async_ld16(pA[c] + kk, &As[b][lofs[c]]);
    }
#pragma unroll
    for (int c = 0; c < 4; ++c) async_ld16(pB[c] + kk, &Ws[b][lofs[c]]);
  };

  const int niter = Kd >> 6;
  stage(0, 0);  // prologue
  for (int it = 0; it < niter; ++it) {
    const int cur = it & 1;
    __syncthreads();  // drains buf[cur] loads (in flight during prev compute)
    if (it + 1 < niter) stage((it + 1) << 6, cur ^ 1);
    const char* AsB = (const char*)As[cur];
    const char* WsB = (const char*)Ws[cur];
#pragma unroll
    for (int s = 0; s < 2; ++s) {
      const int koff = (((s << 2) + quad) ^ (l15 & 7)) * 16;
      short8 af[4], bfr[4];
#pragma unroll
      for (int i = 0; i < 4; ++i)
        af[i] = *(const short8*)(AsB + (size_t)(mrow + i * 16 + l15) * 128 + koff);
#pragma unroll
      for (int j = 0; j < 4; ++j)
        bfr[j] = *(const short8*)(WsB + (size_t)(nrow + j * 16 + l15) * 128 + koff);
#pragma unroll
      for (int i = 0; i < 4; ++i)
#pragma unroll
        for (int j = 0; j < 4; ++j)
          acc[i][j] = __builtin_amdgcn_mfma_f32_16x16x32_bf16(af[i], bfr[j],
                                                              acc[i][j], 0, 0, 0);
    }
  }

  // Epilogue. C/D layout: row(m)=quad*4+reg, col(n)=lane&15 per 16x16 frag.
  const float* extraF = (const float*)extra;
  const unsigned short* extraB = (const unsigned short*)extra;
  float bj[4];
#pragma unroll
  for (int j = 0; j < 4; ++j) {
    const int n = n0 + nrow + j * 16 + l15;
    bj[j] = bias[n];
    if (EPI == 1) bj[j] += extraF[n];
  }
  unsigned short* outb = (unsigned short*)Cout;
#pragma unroll
  for (int i = 0; i < 4; ++i) {
    const int mbase = m0 + mrow + i * 16 + quad * 4;
#pragma unroll
    for (int r = 0; r < 4; ++r) {
      const int m = mbase + r;
      const size_t orow =
          (MAP == 1) ? ((size_t)(m >> 10) * Sc + 2 + (m & 1023)) : (size_t)m;
      const size_t ro = orow * (size_t)ldc + n0 + nrow + l15;
#pragma unroll
      for (int j = 0; j < 4; ++j) {
        float v = acc[i][j][r] + bj[j];
        if (EPI == 2) v += bf2f(extraB[ro + j * 16]);
        if (EPI == 3) v = gelu_fast(v);
        outb[ro + j * 16] = f2bf(v);
      }
    }
  }
}

// ---------------------------------------------------------------------------
// Mega weight cast: one dispatch, 10 (src fp32, dst bf16, n4) entries.
// ---------------------------------------------------------------------------
struct CastTab {
  const float* src[10];
  unsigned short* dst[10];
  int n4[10];
};
__global__ __launch_bounds__(256) void cast_multi(CastTab t) {
  const int e = blockIdx.y;
  const int n4 = t.n4[e];
  const float4* s = (const float4*)t.src[e];
  ushort4* d = (ushort4*)t.dst[e];
  for (int i = blockIdx.x * 256 + threadIdx.x; i < n4; i += gridDim.x * 256) {
    float4 f = s[i];
    ushort4 o;
    o.x = f2bf(f.x); o.y = f2bf(f.y); o.z = f2bf(f.z); o.w = f2bf(f.w);
    d[i] = o;
  }
}

// Concatenate bq|bk|bv (fp32) per layer into qkvb [L][768].
__global__ __launch_bounds__(256) void bias_concat(const float* bq, const float* bk,
                                                   const float* bv, float* qkvb) {
  const int i = blockIdx.x * 256 + threadIdx.x;
  if (i >= 2 * 768) return;
  const int l = i / 768;
  const int j = i - l * 768;
  float v;
  if (j < 256) v = bq[l * 256 + j];
  else if (j < 512) v = bk[l * 256 + j - 256];
  else v = bv[l * 256 + j - 512];
  qkvb[i] = v;
}

// ---------------------------------------------------------------------------
// Query projection (row s=0) + dustbin token (row s=1) -> bf16 x.
// ---------------------------------------------------------------------------
__global__ __launch_bounds__(256) void embed_qd(
    const float* __restrict__ qin, const float* __restrict__ qp_w,
    const float* __restrict__ qp_b, const float* __restrict__ dustbin,
    const float* __restrict__ type_emb, unsigned short* __restrict__ x) {
  const int b = blockIdx.x;
  const int d = threadIdx.x;
  __shared__ __align__(16) float qs[512];
  qs[d] = qin[b * 512 + d];
  qs[d + 256] = qin[b * 512 + 256 + d];
  __syncthreads();
  float acc = 0.0f;
  const float* wr = qp_w + (size_t)d * 512;
#pragma unroll 4
  for (int c = 0; c < 512; c += 4) {
    float4 w4 = *(const float4*)(wr + c);
    acc = fmaf(qs[c], w4.x, acc);
    acc = fmaf(qs[c + 1], w4.y, acc);
    acc = fmaf(qs[c + 2], w4.z, acc);
    acc = fmaf(qs[c + 3], w4.w, acc);
  }
  const size_t base = (size_t)b * Sc * Dc;
  x[base + d] = f2bf(acc + qp_b[d] + type_emb[d]);
  x[base + Dc + d] = f2bf(dustbin[d] + type_emb[Dc + d]);
}

// ---------------------------------------------------------------------------
// LayerNorm: bf16 in, bf16 out. One wave per row; 4 rows/block.
// ---------------------------------------------------------------------------
__global__ __launch_bounds__(256) void ln_kernel(
    const unsigned short* __restrict__ x, const float* __restrict__ w,
    const float* __restrict__ b, unsigned short* __restrict__ y, int nrows) {
  const int wave = threadIdx.x >> 6;
  const int lane = threadIdx.x & 63;
  const int row = blockIdx.x * 4 + wave;
  if (row >= nrows) return;
  const unsigned short* xr = x + (size_t)row * Dc;
  ushort4 xv = *(const ushort4*)(xr + lane * 4);
  const float v0 = bf2f(xv.x), v1 = bf2f(xv.y), v2 = bf2f(xv.z), v3 = bf2f(xv.w);
  float s = v0 + v1 + v2 + v3;
  float sq = v0 * v0 + v1 * v1 + v2 * v2 + v3 * v3;
  s = wave_sum(s);
  sq = wave_sum(sq);
  const float mean = s * (1.0f / Dc);
  const float var = sq * (1.0f / Dc) - mean * mean;
  const float rs = rsqrtf(var + EPSc);
  float4 wv = *(const float4*)(w + lane * 4);
  float4 bv = *(const float4*)(b + lane * 4);
  ushort4 o;
  o.x = f2bf((v0 - mean) * rs * wv.x + bv.x);
  o.y = f2bf((v1 - mean) * rs * wv.y + bv.y);
  o.z = f2bf((v2 - mean) * rs * wv.z + bv.z);
  o.w = f2bf((v3 - mean) * rs * wv.w + bv.w);
  *(ushort4*)(y + (size_t)row * Dc + lane * 4) = o;
}

// ---------------------------------------------------------------------------
// Global-token attention over fused qkv [BS][768] bf16 (q|k|v). Out ao bf16.
// ---------------------------------------------------------------------------
__global__ __launch_bounds__(256) void attn_global(
    const unsigned short* __restrict__ qkv, const unsigned char* __restrict__ mask,
    unsigned short* __restrict__ ao) {
  const int b = blockIdx.x;
  const int h = blockIdx.y;
  const int tid = threadIdx.x;
  const int wv = tid >> 6;
  const int lane = tid & 63;
  __shared__ float q0s[64], q1s[64];
  __shared__ float sc0[Sc], sc1[Sc];
  __shared__ float rbuf[4][2];
  __shared__ float obuf[2][4][64];
  const size_t base = (size_t)b * Sc * 768 + h * 64;
  if (tid < 64) {
    q0s[tid] = bf2f(qkv[base + tid]);
    q1s[tid] = bf2f(qkv[base + 768 + tid]);
  }
  __syncthreads();

  float lm0 = -INFINITY, lm1 = -INFINITY;
  for (int s = tid; s < Sc; s += 256) {
    const unsigned short* kr = qkv + base + 256 + (size_t)s * 768;
    float d0 = 0.0f, d1 = 0.0f;
#pragma unroll
    for (int c = 0; c < 64; c += 8) {
      u16x8 kv = *(const u16x8*)(kr + c);
#pragma unroll
      for (int e = 0; e < 8; ++e) {
        const float kf = bf2f(kv[e]);
        d0 = fmaf(q0s[c + e], kf, d0);
        d1 = fmaf(q1s[c + e], kf, d1);
      }
    }
    const bool pad = (s >= 2) && (mask[b * Kc + (s - 2)] == 0);
    const float s0 = pad ? -INFINITY : d0 * SCALEc;
    const float s1 = pad ? -INFINITY : d1 * SCALEc;
    sc0[s] = s0; sc1[s] = s1;
    lm0 = fmaxf(lm0, s0); lm1 = fmaxf(lm1, s1);
  }
  lm0 = wave_max(lm0);
  lm1 = wave_max(lm1);
  if (lane == 0) { rbuf[wv][0] = lm0; rbuf[wv][1] = lm1; }
  __syncthreads();
  const float m0 = fmaxf(fmaxf(rbuf[0][0], rbuf[1][0]), fmaxf(rbuf[2][0], rbuf[3][0]));
  const float m1 = fmaxf(fmaxf(rbuf[0][1], rbuf[1][1]), fmaxf(rbuf[2][1], rbuf[3][1]));
  float ls0 = 0.0f, ls1 = 0.0f;
  for (int s = tid; s < Sc; s += 256) {
    const float e0 = expf(sc0[s] - m0);
    const float e1 = expf(sc1[s] - m1);
    sc0[s] = e0; sc1[s] = e1;
    ls0 += e0; ls1 += e1;
  }
  ls0 = wave_sum(ls0);
  ls1 = wave_sum(ls1);
  __syncthreads();
  if (lane == 0) { rbuf[wv][0] = ls0; rbuf[wv][1] = ls1; }
  __syncthreads();
  const float t0 = rbuf[0][0] + rbuf[1][0] + rbuf[2][0] + rbuf[3][0];
  const float t1 = rbuf[0][1] + rbuf[1][1] + rbuf[2][1] + rbuf[3][1];
  float o0 = 0.0f, o1 = 0.0f;
  for (int s = wv; s < Sc; s += 4) {
    const float vvv = bf2f(qkv[base + 512 + (size_t)s * 768 + lane]);
    o0 = fmaf(sc0[s], vvv, o0);
    o1 = fmaf(sc1[s], vvv, o1);
  }
  obuf[0][wv][lane] = o0;
  obuf[1][wv][lane] = o1;
  __syncthreads();
  if (wv == 0) {
    const float a0 = obuf[0][0][lane] + obuf[0][1][lane] + obuf[0][2][lane] + obuf[0][3][lane];
    const float a1 = obuf[1][0][lane] + obuf[1][1][lane] + obuf[1][2][lane] + obuf[1][3][lane];
    const size_t ob = ((size_t)b * Sc) * Dc + h * 64;
    ao[ob + lane] = f2bf(a0 / t0);
    ao[ob + Dc + lane] = f2bf(a1 / t1);
  }
}

// ---------------------------------------------------------------------------
// Candidate attention over fused qkv: {global0, global1, self}. Out ao bf16.
// ---------------------------------------------------------------------------
__global__ __launch_bounds__(256) void attn_cand(
    const unsigned short* __restrict__ qkv, const unsigned char* __restrict__ mask,
    unsigned short* __restrict__ ao) {
  const int bk = blockIdx.x;
  const int b = bk >> 10;
  const int kk = bk & 1023;
  const int h = threadIdx.x >> 6;
  const int lane = threadIdx.x & 63;
  const size_t rowg = (size_t)b * Sc * 768 + h * 64;
  const size_t rowc = rowg + (size_t)(2 + kk) * 768;
  const float qc = bf2f(qkv[rowc + lane]);
  float p0 = qc * bf2f(qkv[rowg + 256 + lane]);
  float p1 = qc * bf2f(qkv[rowg + 256 + 768 + lane]);
  float p2 = qc * bf2f(qkv[rowc + 256 + lane]);
#pragma unroll
  for (int off = 32; off > 0; off >>= 1) {
    p0 += __shfl_xor(p0, off, 64);
    p1 += __shfl_xor(p1, off, 64);
    p2 += __shfl_xor(p2, off, 64);
  }
  const bool pad = (mask[b * Kc + kk] == 0);
  const float s0 = p0 * SCALEc;
  const float s1 = p1 * SCALEc;
  const float s2 = pad ? -INFINITY : p2 * SCALEc;
  const float m = fmaxf(fmaxf(s0, s1), s2);
  const float e0 = expf(s0 - m);
  const float e1 = expf(s1 - m);
  const float e2 = pad ? 0.0f : expf(s2 - m);
  const float inv = 1.0f / (e0 + e1 + e2);
  const float o = (e0 * bf2f(qkv[rowg + 512 + lane]) +
                   e1 * bf2f(qkv[rowg + 512 + 768 + lane]) +
                   e2 * bf2f(qkv[rowc + 512 + lane])) * inv;
  ao[((size_t)b * Sc + 2 + kk) * Dc + h * 64 + lane] = f2bf(o);
}

// ---------------------------------------------------------------------------
// Head: LN + dot(head_w) + head_b, mask-scatter into out (B, 1025). bf16 x.
// ---------------------------------------------------------------------------
__global__ __launch_bounds__(256) void head_kernel(
    const unsigned short* __restrict__ x, const float* __restrict__ lnw,
    const float* __restrict__ lnb, const float* __restrict__ hw,
    const float* __restrict__ hb, const unsigned char* __restrict__ mask,
    float* __restrict__ out) {
  const int gw = blockIdx.x * 4 + (threadIdx.x >> 6);
  const int lane = threadIdx.x & 63;
  if (gw >= Bc * 1025) return;
  const int b = gw / 1025;
  const int j = gw - b * 1025;
  const int s = 1 + j;
  const unsigned short* xr = x + ((size_t)b * Sc + s) * Dc;
  ushort4 xv = *(const ushort4*)(xr + lane * 4);
  const float v0 = bf2f(xv.x), v1 = bf2f(xv.y), v2 = bf2f(xv.z), v3 = bf2f(xv.w);
  float su = v0 + v1 + v2 + v3;
  float sq = v0 * v0 + v1 * v1 + v2 * v2 + v3 * v3;
  su = wave_sum(su);
  sq = wave_sum(sq);
  const float mean = su * (1.0f / Dc);
  const float var = sq * (1.0f / Dc) - mean * mean;
  const float rs = rsqrtf(var + EPSc);
  float4 wv = *(const float4*)(lnw + lane * 4);
  float4 bv = *(const float4*)(lnb + lane * 4);
  float4 hv = *(const float4*)(hw + lane * 4);
  float d = ((v0 - mean) * rs * wv.x + bv.x) * hv.x +
            ((v1 - mean) * rs * wv.y + bv.y) * hv.y +
            ((v2 - mean) * rs * wv.z + bv.z) * hv.z +
            ((v3 - mean) * rs * wv.w + bv.w) * hv.w;
  d = wave_sum(d);
  if (lane == 0) {
    const float logit = d + hb[0];
    float res;
    if (j == 0) res = logit;
    else res = (mask[b * Kc + (j - 1)] != 0) ? logit : NEG_OUT;
    out[(size_t)b * 1025 + j] = res;
  }
}

// ---------------------------------------------------------------------------
extern "C" void kernel_launch(void* const* d_in, const int* in_sizes, int n_in,
                              void* d_out, int out_size, void* d_ws,
                              size_t ws_size, hipStream_t stream) {
  const float* query = (const float*)d_in[0];
  const float* cands = (const float*)d_in[1];
  const unsigned char* mask = (const unsigned char*)d_in[2];
  const float* qp_w = (const float*)d_in[3];
  const float* qp_b = (const float*)d_in[4];
  const float* cp_w = (const float*)d_in[5];
  const float* cp_b = (const float*)d_in[6];
  const float* dustbin = (const float*)d_in[7];
  const float* type_emb = (const float*)d_in[8];
  const float* ln1_w = (const float*)d_in[9];
  const float* ln1_b = (const float*)d_in[10];
  const float* ln2_w = (const float*)d_in[11];
  const float* ln2_b = (const float*)d_in[12];
  const float* Wq = (const float*)d_in[13];
  const float* bq = (const float*)d_in[14];
  const float* Wk = (const float*)d_in[15];
  const float* bk = (const float*)d_in[16];
  const float* Wv = (const float*)d_in[17];
  const float* bv = (const float*)d_in[18];
  const float* Wo = (const float*)d_in[19];
  const float* bo = (const float*)d_in[20];
  const float* f1w = (const float*)d_in[21];
  const float* f1b = (const float*)d_in[22];
  const float* f2w = (const float*)d_in[23];
  const float* f2b = (const float*)d_in[24];
  const float* hlw = (const float*)d_in[25];
  const float* hlb = (const float*)d_in[26];
  const float* hw = (const float*)d_in[27];
  const float* hb = (const float*)d_in[28];
  float* out = (float*)d_out;

  const size_t XSZ = (size_t)Bc * Sc * Dc;       // 16,809,984
  const size_t FFSZ = (size_t)Bc * Sc * FFc;     // 67,239,936 (>= BS*768)

  char* p = (char*)d_ws;
  unsigned short* x = (unsigned short*)p;   p += XSZ * 2;   // bf16 residual
  unsigned short* y = (unsigned short*)p;   p += XSZ * 2;
  unsigned short* ao = (unsigned short*)p;  p += XSZ * 2;
  unsigned short* big = (unsigned short*)p; p += FFSZ * 2;
  unsigned short* qkv = big;                // [BS][768], overlapped with ff
  unsigned short* ff = big;                 // [BS][1024]
  unsigned short* cpw_b = (unsigned short*)p;      // 256x512
  unsigned short* qkvw_b = cpw_b + 131072;          // [L][768][256]
  unsigned short* Wo_b = qkvw_b + 2 * 768 * 256;    // [L][256][256]
  unsigned short* f1_b = Wo_b + 131072;             // [L][1024][256]
  unsigned short* f2_b = f1_b + 524288;             // [L][256][1024]
  float* qkvb = (float*)(f2_b + 524288);            // [L][768]

  const int BS = Bc * Sc;  // 65664 = 513*128

  // One mega-cast for all weights (10 entries).
  CastTab t;
  t.src[0] = cp_w;  t.dst[0] = cpw_b; t.n4[0] = 131072 / 4;
  t.src[1] = Wo;    t.dst[1] = Wo_b;  t.n4[1] = 131072 / 4;
  t.src[2] = f1w;   t.dst[2] = f1_b;  t.n4[2] = 524288 / 4;
  t.src[3] = f2w;   t.dst[3] = f2_b;  t.n4[3] = 524288 / 4;
  for (int l = 0; l < 2; ++l) {
    t.src[4 + l * 3 + 0] = Wq + l * 65536;
    t.src[4 + l * 3 + 1] = Wk + l * 65536;
    t.src[4 + l * 3 + 2] = Wv + l * 65536;
    t.dst[4 + l * 3 + 0] = qkvw_b + l * 196608 + 0 * 65536;
    t.dst[4 + l * 3 + 1] = qkvw_b + l * 196608 + 1 * 65536;
    t.dst[4 + l * 3 + 2] = qkvw_b + l * 196608 + 2 * 65536;
    t.n4[4 + l * 3 + 0] = 65536 / 4;
    t.n4[4 + l * 3 + 1] = 65536 / 4;
    t.n4[4 + l * 3 + 2] = 65536 / 4;
  }
  cast_multi<<<dim3(128, 10), 256, 0, stream>>>(t);
  bias_concat<<<6, 256, 0, stream>>>(bq, bk, bv, qkvb);

  // Embed: candidates (fp32, fused cast) -> x rows [2,1026); rows 0,1 direct.
  gemm_mfma<1, 1, 1><<<dim3(Bc * Kc / 128, Dc / 128), 256, 0, stream>>>(
      cands, cpw_b, cp_b, type_emb + 2 * Dc, x, Dc, Cc, Dc);
  embed_qd<<<Bc, 256, 0, stream>>>(query, qp_w, qp_b, dustbin, type_emb, x);

  for (int l = 0; l < 2; ++l) {
    ln_kernel<<<BS / 4, 256, 0, stream>>>(x, ln1_w + l * Dc, ln1_b + l * Dc, y, BS);
    // Fused QKV: N=768, out pitch 768.
    gemm_mfma<4, 0, 0><<<dim3(BS / 128, 768 / 128), 256, 0, stream>>>(
        y, qkvw_b + l * 196608, qkvb + l * 768, nullptr, qkv, 768, Dc, 768);
    attn_global<<<dim3(Bc, Hc), 256, 0, stream>>>(qkv, mask, ao);
    attn_cand<<<Bc * Kc, 256, 0, stream>>>(qkv, mask, ao);
    gemm_mfma<2, 0, 0><<<dim3(BS / 128, Dc / 128), 256, 0, stream>>>(
        ao, Wo_b + l * 65536, bo + l * Dc, x, x, Dc, Dc, Dc);
    ln_kernel<<<BS / 4, 256, 0, stream>>>(x, ln2_w + l * Dc, ln2_b + l * Dc, y, BS);
    gemm_mfma<3, 0, 0><<<dim3(BS / 128, FFc / 128), 256, 0, stream>>>(
        y, f1_b + l * 524288 / 2, f1b + l * FFc, nullptr, ff, FFc, Dc, FFc);
    gemm_mfma<2, 0, 0><<<dim3(BS / 128, Dc / 128), 256, 0, stream>>>(
        ff, f2_b + l * 524288 / 2, f2b + l * Dc, x, x, Dc, FFc, Dc);
  }

  head_kernel<<<(Bc * 1025 + 3) / 4, 256, 0, stream>>>(x, hlw, hlb, hw, hb, mask, out);
}

// Round 7
// 1071.642 us; speedup vs baseline: 1.2330x; 1.2330x over previous
//
#include <hip/hip_runtime.h>
#include <math.h>

// Model constants
static constexpr int Bc = 64;
static constexpr int Kc = 1024;
static constexpr int Cc = 512;
static constexpr int Dc = 256;
static constexpr int Hc = 4;
static constexpr int Sc = 1026;       // 2 + K
static constexpr int FFc = 1024;
static constexpr float EPSc = 1e-5f;
static constexpr float SCALEc = 0.125f;   // 1/sqrt(64)
static constexpr float NEG_OUT = -1.0e30f;  // finite stand-in for -inf (see R1)

typedef __attribute__((ext_vector_type(8))) short short8;
typedef __attribute__((ext_vector_type(8))) unsigned short u16x8;
typedef __attribute__((ext_vector_type(4))) float f32x4;

__device__ __forceinline__ float bf2f(unsigned short u) {
  union { float f; unsigned int i; } c; c.i = ((unsigned int)u) << 16; return c.f;
}
__device__ __forceinline__ unsigned short f2bf(float f) {
  union { float f; unsigned int i; } c; c.f = f;
  unsigned int i = c.i;
  unsigned int r = (i + 0x7fffu + ((i >> 16) & 1u)) >> 16;  // RNE
  return (unsigned short)r;
}

__device__ __forceinline__ float wave_sum(float v) {
#pragma unroll
  for (int off = 32; off > 0; off >>= 1) v += __shfl_xor(v, off, 64);
  return v;
}
__device__ __forceinline__ float wave_max(float v) {
#pragma unroll
  for (int off = 32; off > 0; off >>= 1) v = fmaxf(v, __shfl_xor(v, off, 64));
  return v;
}

__device__ __forceinline__ void async_ld16(const unsigned short* g, unsigned short* l) {
  __builtin_amdgcn_global_load_lds(
      (const __attribute__((address_space(1))) void*)g,
      (__attribute__((address_space(3))) void*)l, 16, 0, 0);
}

// Fast GELU: tanh-form, err ~1e-3 relative (below bf16 rounding).
__device__ __forceinline__ float gelu_fast(float u) {
  const float z = 1.5957691216057308f * u * (1.0f + 0.044715f * u * u);
  return u / (1.0f + __expf(-z));
}

// ---------------------------------------------------------------------------
// bf16 MFMA GEMM, BK=32, double-buffered LDS (32 KB), one barrier per iter.
// 1D grid, XCD-aware swizzle: consecutive slots on ONE XCD sweep all N-blocks
// of one M-group so the A-tile stays hot in that XCD's 4 MB L2
// (blockIdx -> XCD is round-robin %8 on MI355X).
// Bank swizzle: k-chunk XOR (row>>1)&3 on both stage & read sides; residual
// aliasing is the free 2-way (lanes r, r+8).
// A: [M][Kd] bf16 (CASTA=0) or fp32 (CASTA=1, cast fused into staging).
// W: [N][Kd] bf16. EPI: 1 +extraF[n] (type-emb); 2 +bf16 extraB[orow*ldc+n]
// (residual, in-place OK); 3 fast GELU; 4 bias only. Outputs bf16.
// MAP: 1 = candidate row scatter m -> (m>>10)*1026+2+(m&1023).
// ---------------------------------------------------------------------------
template <int EPI, int MAP, int CASTA>
__global__ __launch_bounds__(256) void gemm_mfma(
    const void* __restrict__ Av, const unsigned short* __restrict__ W,
    const float* __restrict__ bias, const void* extra,
    void* Cout, int N, int Kd, int ldc, int MB, int NB) {
  __shared__ unsigned short As[2][4096];  // [128 rows][32 k] = 8 KB per buf
  __shared__ unsigned short Ws[2][4096];
  const int xcd = blockIdx.x & 7;
  const int slot = blockIdx.x >> 3;
  const int nb = slot % NB;
  const int mb = (slot / NB) * 8 + xcd;
  if (mb >= MB) return;
  const int m0 = mb * 128;
  const int n0 = nb * 128;
  const int tid = threadIdx.x;
  const int w = tid >> 6;
  const int lane = tid & 63;

  const unsigned short* A = (const unsigned short*)Av;
  const float* Af = (const float*)Av;

  // Staging: wave w, call c (0/1) covers rows [(w*2+c)*16, +16); 4 lanes/row,
  // 16 B each. Phys chunk = lane&3; global chunk XOR (row>>1)&3.
  const int srA[2] = {(w * 2 + 0) * 16 + (lane >> 2), (w * 2 + 1) * 16 + (lane >> 2)};
  const unsigned short* pA[2];
  const unsigned short* pB[2];
#pragma unroll
  for (int c = 0; c < 2; ++c) {
    const int kc = ((lane & 3) ^ ((srA[c] >> 1) & 3)) * 8;
    if (!CASTA) pA[c] = A + (size_t)(m0 + srA[c]) * Kd + kc;
    pB[c] = W + (size_t)(n0 + srA[c]) * Kd + kc;
  }
  const int lreg0 = (w * 2 + 0) * 512;
  const int lreg1 = (w * 2 + 1) * 512;

  f32x4 zero = {0.f, 0.f, 0.f, 0.f};
  f32x4 acc[4][4];
#pragma unroll
  for (int i = 0; i < 4; ++i)
#pragma unroll
    for (int j = 0; j < 4; ++j) acc[i][j] = zero;

  const int mrow = (w & 1) * 64;
  const int nrow = (w >> 1) * 64;
  const int l15 = lane & 15;
  const int quad = lane >> 4;
  const int koff = (quad ^ ((l15 >> 1) & 3)) * 16;  // byte offset of k-chunk

  auto stage = [&](int kk, int b) {
    if (CASTA) {
      // fp32 A -> bf16 LDS: 4 x (float4 load, cvt, 8B ds_write), same swizzle.
#pragma unroll
      for (int wi = 0; wi < 4; ++wi) {
        const int g = wi * 256 + tid;     // 0..1023
        const int row = g >> 3;
        const int k4 = g & 7;
        const int phys =
            row * 32 + ((((k4 >> 1) ^ ((row >> 1) & 3))) << 3) + ((k4 & 1) << 2);
        const float4 a4 =
            *(const float4*)(Af + (size_t)(m0 + row) * Kd + kk + k4 * 4);
        ushort4 o;
        o.x = f2bf(a4.x); o.y = f2bf(a4.y); o.z = f2bf(a4.z); o.w = f2bf(a4.w);
        *(ushort4*)(&As[b][phys]) = o;
      }
    } else {
      async_ld16(pA[0] + kk, &As[b][lreg0]);
      async_ld16(pA[1] + kk, &As[b][lreg1]);
    }
    async_ld16(pB[0] + kk, &Ws[b][lreg0]);
    async_ld16(pB[1] + kk, &Ws[b][lreg1]);
  };

  const int niter = Kd >> 5;
  stage(0, 0);  // prologue
  for (int it = 0; it < niter; ++it) {
    const int cur = it & 1;
    __syncthreads();  // drains buf[cur] loads (in flight during prev compute)
    if (it + 1 < niter) stage((it + 1) << 5, cur ^ 1);
    const char* AsB = (const char*)As[cur];
    const char* WsB = (const char*)Ws[cur];
    short8 af[4], bfr[4];
#pragma unroll
    for (int i = 0; i < 4; ++i)
      af[i] = *(const short8*)(AsB + (size_t)(mrow + i * 16 + l15) * 64 + koff);
#pragma unroll
    for (int j = 0; j < 4; ++j)
      bfr[j] = *(const short8*)(WsB + (size_t)(nrow + j * 16 + l15) * 64 + koff);
#pragma unroll
    for (int i = 0; i < 4; ++i)
#pragma unroll
      for (int j = 0; j < 4; ++j)
        acc[i][j] = __builtin_amdgcn_mfma_f32_16x16x32_bf16(af[i], bfr[j],
                                                            acc[i][j], 0, 0, 0);
  }

  // Epilogue. C/D layout: row(m)=quad*4+reg, col(n)=lane&15 per 16x16 frag.
  const float* extraF = (const float*)extra;
  const unsigned short* extraB = (const unsigned short*)extra;
  float bj[4];
#pragma unroll
  for (int j = 0; j < 4; ++j) {
    const int n = n0 + nrow + j * 16 + l15;
    bj[j] = bias[n];
    if (EPI == 1) bj[j] += extraF[n];
  }
  unsigned short* outb = (unsigned short*)Cout;
#pragma unroll
  for (int i = 0; i < 4; ++i) {
    const int mbase = m0 + mrow + i * 16 + quad * 4;
#pragma unroll
    for (int r = 0; r < 4; ++r) {
      const int m = mbase + r;
      const size_t orow =
          (MAP == 1) ? ((size_t)(m >> 10) * Sc + 2 + (m & 1023)) : (size_t)m;
      const size_t ro = orow * (size_t)ldc + n0 + nrow + l15;
#pragma unroll
      for (int j = 0; j < 4; ++j) {
        float v = acc[i][j][r] + bj[j];
        if (EPI == 2) v += bf2f(extraB[ro + j * 16]);
        if (EPI == 3) v = gelu_fast(v);
        outb[ro + j * 16] = f2bf(v);
      }
    }
  }
}

// ---------------------------------------------------------------------------
// Mega weight cast: one dispatch, 10 (src fp32, dst bf16, n4) entries.
// ---------------------------------------------------------------------------
struct CastTab {
  const float* src[10];
  unsigned short* dst[10];
  int n4[10];
};
__global__ __launch_bounds__(256) void cast_multi(CastTab t) {
  const int e = blockIdx.y;
  const int n4 = t.n4[e];
  const float4* s = (const float4*)t.src[e];
  ushort4* d = (ushort4*)t.dst[e];
  for (int i = blockIdx.x * 256 + threadIdx.x; i < n4; i += gridDim.x * 256) {
    float4 f = s[i];
    ushort4 o;
    o.x = f2bf(f.x); o.y = f2bf(f.y); o.z = f2bf(f.z); o.w = f2bf(f.w);
    d[i] = o;
  }
}

// Concatenate bq|bk|bv (fp32) per layer into qkvb [L][768].
__global__ __launch_bounds__(256) void bias_concat(const float* bq, const float* bk,
                                                   const float* bv, float* qkvb) {
  const int i = blockIdx.x * 256 + threadIdx.x;
  if (i >= 2 * 768) return;
  const int l = i / 768;
  const int j = i - l * 768;
  float v;
  if (j < 256) v = bq[l * 256 + j];
  else if (j < 512) v = bk[l * 256 + j - 256];
  else v = bv[l * 256 + j - 512];
  qkvb[i] = v;
}

// ---------------------------------------------------------------------------
// Query projection (row s=0) + dustbin token (row s=1) -> bf16 x.
// ---------------------------------------------------------------------------
__global__ __launch_bounds__(256) void embed_qd(
    const float* __restrict__ qin, const float* __restrict__ qp_w,
    const float* __restrict__ qp_b, const float* __restrict__ dustbin,
    const float* __restrict__ type_emb, unsigned short* __restrict__ x) {
  const int b = blockIdx.x;
  const int d = threadIdx.x;
  __shared__ __align__(16) float qs[512];
  qs[d] = qin[b * 512 + d];
  qs[d + 256] = qin[b * 512 + 256 + d];
  __syncthreads();
  float acc = 0.0f;
  const float* wr = qp_w + (size_t)d * 512;
#pragma unroll 4
  for (int c = 0; c < 512; c += 4) {
    float4 w4 = *(const float4*)(wr + c);
    acc = fmaf(qs[c], w4.x, acc);
    acc = fmaf(qs[c + 1], w4.y, acc);
    acc = fmaf(qs[c + 2], w4.z, acc);
    acc = fmaf(qs[c + 3], w4.w, acc);
  }
  const size_t base = (size_t)b * Sc * Dc;
  x[base + d] = f2bf(acc + qp_b[d] + type_emb[d]);
  x[base + Dc + d] = f2bf(dustbin[d] + type_emb[Dc + d]);
}

// ---------------------------------------------------------------------------
// LayerNorm: bf16 in, bf16 out. One wave per row; 4 rows/block.
// ---------------------------------------------------------------------------
__global__ __launch_bounds__(256) void ln_kernel(
    const unsigned short* __restrict__ x, const float* __restrict__ w,
    const float* __restrict__ b, unsigned short* __restrict__ y, int nrows) {
  const int wave = threadIdx.x >> 6;
  const int lane = threadIdx.x & 63;
  const int row = blockIdx.x * 4 + wave;
  if (row >= nrows) return;
  const unsigned short* xr = x + (size_t)row * Dc;
  ushort4 xv = *(const ushort4*)(xr + lane * 4);
  const float v0 = bf2f(xv.x), v1 = bf2f(xv.y), v2 = bf2f(xv.z), v3 = bf2f(xv.w);
  float s = v0 + v1 + v2 + v3;
  float sq = v0 * v0 + v1 * v1 + v2 * v2 + v3 * v3;
  s = wave_sum(s);
  sq = wave_sum(sq);
  const float mean = s * (1.0f / Dc);
  const float var = sq * (1.0f / Dc) - mean * mean;
  const float rs = rsqrtf(var + EPSc);
  float4 wv = *(const float4*)(w + lane * 4);
  float4 bv = *(const float4*)(b + lane * 4);
  ushort4 o;
  o.x = f2bf((v0 - mean) * rs * wv.x + bv.x);
  o.y = f2bf((v1 - mean) * rs * wv.y + bv.y);
  o.z = f2bf((v2 - mean) * rs * wv.z + bv.z);
  o.w = f2bf((v3 - mean) * rs * wv.w + bv.w);
  *(ushort4*)(y + (size_t)row * Dc + lane * 4) = o;
}

// ---------------------------------------------------------------------------
// Global-token attention over fused qkv [BS][768] bf16 (q|k|v). Out ao bf16.
// ---------------------------------------------------------------------------
__global__ __launch_bounds__(256) void attn_global(
    const unsigned short* __restrict__ qkv, const unsigned char* __restrict__ mask,
    unsigned short* __restrict__ ao) {
  const int b = blockIdx.x;
  const int h = blockIdx.y;
  const int tid = threadIdx.x;
  const int wv = tid >> 6;
  const int lane = tid & 63;
  __shared__ float q0s[64], q1s[64];
  __shared__ float sc0[Sc], sc1[Sc];
  __shared__ float rbuf[4][2];
  __shared__ float obuf[2][4][64];
  const size_t base = (size_t)b * Sc * 768 + h * 64;
  if (tid < 64) {
    q0s[tid] = bf2f(qkv[base + tid]);
    q1s[tid] = bf2f(qkv[base + 768 + tid]);
  }
  __syncthreads();

  float lm0 = -INFINITY, lm1 = -INFINITY;
  for (int s = tid; s < Sc; s += 256) {
    const unsigned short* kr = qkv + base + 256 + (size_t)s * 768;
    float d0 = 0.0f, d1 = 0.0f;
#pragma unroll
    for (int c = 0; c < 64; c += 8) {
      u16x8 kv = *(const u16x8*)(kr + c);
#pragma unroll
      for (int e = 0; e < 8; ++e) {
        const float kf = bf2f(kv[e]);
        d0 = fmaf(q0s[c + e], kf, d0);
        d1 = fmaf(q1s[c + e], kf, d1);
      }
    }
    const bool pad = (s >= 2) && (mask[b * Kc + (s - 2)] == 0);
    const float s0 = pad ? -INFINITY : d0 * SCALEc;
    const float s1 = pad ? -INFINITY : d1 * SCALEc;
    sc0[s] = s0; sc1[s] = s1;
    lm0 = fmaxf(lm0, s0); lm1 = fmaxf(lm1, s1);
  }
  lm0 = wave_max(lm0);
  lm1 = wave_max(lm1);
  if (lane == 0) { rbuf[wv][0] = lm0; rbuf[wv][1] = lm1; }
  __syncthreads();
  const float m0 = fmaxf(fmaxf(rbuf[0][0], rbuf[1][0]), fmaxf(rbuf[2][0], rbuf[3][0]));
  const float m1 = fmaxf(fmaxf(rbuf[0][1], rbuf[1][1]), fmaxf(rbuf[2][1], rbuf[3][1]));
  float ls0 = 0.0f, ls1 = 0.0f;
  for (int s = tid; s < Sc; s += 256) {
    const float e0 = expf(sc0[s] - m0);
    const float e1 = expf(sc1[s] - m1);
    sc0[s] = e0; sc1[s] = e1;
    ls0 += e0; ls1 += e1;
  }
  ls0 = wave_sum(ls0);
  ls1 = wave_sum(ls1);
  __syncthreads();
  if (lane == 0) { rbuf[wv][0] = ls0; rbuf[wv][1] = ls1; }
  __syncthreads();
  const float t0 = rbuf[0][0] + rbuf[1][0] + rbuf[2][0] + rbuf[3][0];
  const float t1 = rbuf[0][1] + rbuf[1][1] + rbuf[2][1] + rbuf[3][1];
  float o0 = 0.0f, o1 = 0.0f;
  for (int s = wv; s < Sc; s += 4) {
    const float vvv = bf2f(qkv[base + 512 + (size_t)s * 768 + lane]);
    o0 = fmaf(sc0[s], vvv, o0);
    o1 = fmaf(sc1[s], vvv, o1);
  }
  obuf[0][wv][lane] = o0;
  obuf[1][wv][lane] = o1;
  __syncthreads();
  if (wv == 0) {
    const float a0 = obuf[0][0][lane] + obuf[0][1][lane] + obuf[0][2][lane] + obuf[0][3][lane];
    const float a1 = obuf[1][0][lane] + obuf[1][1][lane] + obuf[1][2][lane] + obuf[1][3][lane];
    const size_t ob = ((size_t)b * Sc) * Dc + h * 64;
    ao[ob + lane] = f2bf(a0 / t0);
    ao[ob + Dc + lane] = f2bf(a1 / t1);
  }
}

// ---------------------------------------------------------------------------
// Candidate attention over fused qkv: {global0, global1, self}. Out ao bf16.
// ---------------------------------------------------------------------------
__global__ __launch_bounds__(256) void attn_cand(
    const unsigned short* __restrict__ qkv, const unsigned char* __restrict__ mask,
    unsigned short* __restrict__ ao) {
  const int bk = blockIdx.x;
  const int b = bk >> 10;
  const int kk = bk & 1023;
  const int h = threadIdx.x >> 6;
  const int lane = threadIdx.x & 63;
  const size_t rowg = (size_t)b * Sc * 768 + h * 64;
  const size_t rowc = rowg + (size_t)(2 + kk) * 768;
  const float qc = bf2f(qkv[rowc + lane]);
  float p0 = qc * bf2f(qkv[rowg + 256 + lane]);
  float p1 = qc * bf2f(qkv[rowg + 256 + 768 + lane]);
  float p2 = qc * bf2f(qkv[rowc + 256 + lane]);
#pragma unroll
  for (int off = 32; off > 0; off >>= 1) {
    p0 += __shfl_xor(p0, off, 64);
    p1 += __shfl_xor(p1, off, 64);
    p2 += __shfl_xor(p2, off, 64);
  }
  const bool pad = (mask[b * Kc + kk] == 0);
  const float s0 = p0 * SCALEc;
  const float s1 = p1 * SCALEc;
  const float s2 = pad ? -INFINITY : p2 * SCALEc;
  const float m = fmaxf(fmaxf(s0, s1), s2);
  const float e0 = expf(s0 - m);
  const float e1 = expf(s1 - m);
  const float e2 = pad ? 0.0f : expf(s2 - m);
  const float inv = 1.0f / (e0 + e1 + e2);
  const float o = (e0 * bf2f(qkv[rowg + 512 + lane]) +
                   e1 * bf2f(qkv[rowg + 512 + 768 + lane]) +
                   e2 * bf2f(qkv[rowc + 512 + lane])) * inv;
  ao[((size_t)b * Sc + 2 + kk) * Dc + h * 64 + lane] = f2bf(o);
}

// ---------------------------------------------------------------------------
// Head: LN + dot(head_w) + head_b, mask-scatter into out (B, 1025). bf16 x.
// ---------------------------------------------------------------------------
__global__ __launch_bounds__(256) void head_kernel(
    const unsigned short* __restrict__ x, const float* __restrict__ lnw,
    const float* __restrict__ lnb, const float* __restrict__ hw,
    const float* __restrict__ hb, const unsigned char* __restrict__ mask,
    float* __restrict__ out) {
  const int gw = blockIdx.x * 4 + (threadIdx.x >> 6);
  const int lane = threadIdx.x & 63;
  if (gw >= Bc * 1025) return;
  const int b = gw / 1025;
  const int j = gw - b * 1025;
  const int s = 1 + j;
  const unsigned short* xr = x + ((size_t)b * Sc + s) * Dc;
  ushort4 xv = *(const ushort4*)(xr + lane * 4);
  const float v0 = bf2f(xv.x), v1 = bf2f(xv.y), v2 = bf2f(xv.z), v3 = bf2f(xv.w);
  float su = v0 + v1 + v2 + v3;
  float sq = v0 * v0 + v1 * v1 + v2 * v2 + v3 * v3;
  su = wave_sum(su);
  sq = wave_sum(sq);
  const float mean = su * (1.0f / Dc);
  const float var = sq * (1.0f / Dc) - mean * mean;
  const float rs = rsqrtf(var + EPSc);
  float4 wv = *(const float4*)(lnw + lane * 4);
  float4 bv = *(const float4*)(lnb + lane * 4);
  float4 hv = *(const float4*)(hw + lane * 4);
  float d = ((v0 - mean) * rs * wv.x + bv.x) * hv.x +
            ((v1 - mean) * rs * wv.y + bv.y) * hv.y +
            ((v2 - mean) * rs * wv.z + bv.z) * hv.z +
            ((v3 - mean) * rs * wv.w + bv.w) * hv.w;
  d = wave_sum(d);
  if (lane == 0) {
    const float logit = d + hb[0];
    float res;
    if (j == 0) res = logit;
    else res = (mask[b * Kc + (j - 1)] != 0) ? logit : NEG_OUT;
    out[(size_t)b * 1025 + j] = res;
  }
}

// ---------------------------------------------------------------------------
extern "C" void kernel_launch(void* const* d_in, const int* in_sizes, int n_in,
                              void* d_out, int out_size, void* d_ws,
                              size_t ws_size, hipStream_t stream) {
  const float* query = (const float*)d_in[0];
  const float* cands = (const float*)d_in[1];
  const unsigned char* mask = (const unsigned char*)d_in[2];
  const float* qp_w = (const float*)d_in[3];
  const float* qp_b = (const float*)d_in[4];
  const float* cp_w = (const float*)d_in[5];
  const float* cp_b = (const float*)d_in[6];
  const float* dustbin = (const float*)d_in[7];
  const float* type_emb = (const float*)d_in[8];
  const float* ln1_w = (const float*)d_in[9];
  const float* ln1_b = (const float*)d_in[10];
  const float* ln2_w = (const float*)d_in[11];
  const float* ln2_b = (const float*)d_in[12];
  const float* Wq = (const float*)d_in[13];
  const float* bq = (const float*)d_in[14];
  const float* Wk = (const float*)d_in[15];
  const float* bk = (const float*)d_in[16];
  const float* Wv = (const float*)d_in[17];
  const float* bv = (const float*)d_in[18];
  const float* Wo = (const float*)d_in[19];
  const float* bo = (const float*)d_in[20];
  const float* f1w = (const float*)d_in[21];
  const float* f1b = (const float*)d_in[22];
  const float* f2w = (const float*)d_in[23];
  const float* f2b = (const float*)d_in[24];
  const float* hlw = (const float*)d_in[25];
  const float* hlb = (const float*)d_in[26];
  const float* hw = (const float*)d_in[27];
  const float* hb = (const float*)d_in[28];
  float* out = (float*)d_out;

  const size_t XSZ = (size_t)Bc * Sc * Dc;       // 16,809,984
  const size_t FFSZ = (size_t)Bc * Sc * FFc;     // 67,239,936 (>= BS*768)

  char* p = (char*)d_ws;
  unsigned short* x = (unsigned short*)p;   p += XSZ * 2;   // bf16 residual
  unsigned short* y = (unsigned short*)p;   p += XSZ * 2;
  unsigned short* ao = (unsigned short*)p;  p += XSZ * 2;
  unsigned short* big = (unsigned short*)p; p += FFSZ * 2;
  unsigned short* qkv = big;                // [BS][768], overlapped with ff
  unsigned short* ff = big;                 // [BS][1024]
  unsigned short* cpw_b = (unsigned short*)p;      // 256x512
  unsigned short* qkvw_b = cpw_b + 131072;          // [L][768][256]
  unsigned short* Wo_b = qkvw_b + 2 * 768 * 256;    // [L][256][256]
  unsigned short* f1_b = Wo_b + 131072;             // [L][1024][256]
  unsigned short* f2_b = f1_b + 524288;             // [L][256][1024]
  float* qkvb = (float*)(f2_b + 524288);            // [L][768]

  const int BS = Bc * Sc;  // 65664 = 513*128
  // Swizzled 1D grid size: NB * (MB rounded up to multiple of 8).
  auto sgrid = [](int MB, int NB) { return (unsigned)(NB * (((MB + 7) >> 3) << 3)); };

  // One mega-cast for all weights (10 entries).
  CastTab t;
  t.src[0] = cp_w;  t.dst[0] = cpw_b; t.n4[0] = 131072 / 4;
  t.src[1] = Wo;    t.dst[1] = Wo_b;  t.n4[1] = 131072 / 4;
  t.src[2] = f1w;   t.dst[2] = f1_b;  t.n4[2] = 524288 / 4;
  t.src[3] = f2w;   t.dst[3] = f2_b;  t.n4[3] = 524288 / 4;
  for (int l = 0; l < 2; ++l) {
    t.src[4 + l * 3 + 0] = Wq + l * 65536;
    t.src[4 + l * 3 + 1] = Wk + l * 65536;
    t.src[4 + l * 3 + 2] = Wv + l * 65536;
    t.dst[4 + l * 3 + 0] = qkvw_b + l * 196608 + 0 * 65536;
    t.dst[4 + l * 3 + 1] = qkvw_b + l * 196608 + 1 * 65536;
    t.dst[4 + l * 3 + 2] = qkvw_b + l * 196608 + 2 * 65536;
    t.n4[4 + l * 3 + 0] = 65536 / 4;
    t.n4[4 + l * 3 + 1] = 65536 / 4;
    t.n4[4 + l * 3 + 2] = 65536 / 4;
  }
  cast_multi<<<dim3(128, 10), 256, 0, stream>>>(t);
  bias_concat<<<6, 256, 0, stream>>>(bq, bk, bv, qkvb);

  // Embed: candidates (fp32, fused cast) -> x rows [2,1026); rows 0,1 direct.
  gemm_mfma<1, 1, 1><<<sgrid(512, 2), 256, 0, stream>>>(
      cands, cpw_b, cp_b, type_emb + 2 * Dc, x, Dc, Cc, Dc, 512, 2);
  embed_qd<<<Bc, 256, 0, stream>>>(query, qp_w, qp_b, dustbin, type_emb, x);

  for (int l = 0; l < 2; ++l) {
    ln_kernel<<<BS / 4, 256, 0, stream>>>(x, ln1_w + l * Dc, ln1_b + l * Dc, y, BS);
    // Fused QKV: N=768, out pitch 768.
    gemm_mfma<4, 0, 0><<<sgrid(513, 6), 256, 0, stream>>>(
        y, qkvw_b + l * 196608, qkvb + l * 768, nullptr, qkv, 768, Dc, 768, 513, 6);
    attn_global<<<dim3(Bc, Hc), 256, 0, stream>>>(qkv, mask, ao);
    attn_cand<<<Bc * Kc, 256, 0, stream>>>(qkv, mask, ao);
    gemm_mfma<2, 0, 0><<<sgrid(513, 2), 256, 0, stream>>>(
        ao, Wo_b + l * 65536, bo + l * Dc, x, x, Dc, Dc, Dc, 513, 2);
    ln_kernel<<<BS / 4, 256, 0, stream>>>(x, ln2_w + l * Dc, ln2_b + l * Dc, y, BS);
    gemm_mfma<3, 0, 0><<<sgrid(513, 8), 256, 0, stream>>>(
        y, f1_b + l * 524288 / 2, f1b + l * FFc, nullptr, ff, FFc, Dc, FFc, 513, 8);
    gemm_mfma<2, 0, 0><<<sgrid(513, 2), 256, 0, stream>>>(
        ff, f2_b + l * 524288 / 2, f2b + l * Dc, x, x, Dc, FFc, Dc, 513, 2);
  }

  head_kernel<<<(Bc * 1025 + 3) / 4, 256, 0, stream>>>(x, hlw, hlb, hw, hb, mask, out);
}

// Round 8
// 983.285 us; speedup vs baseline: 1.3438x; 1.0899x over previous
//
#include <hip/hip_runtime.h>
#include <math.h>

// Model constants
static constexpr int Bc = 64;
static constexpr int Kc = 1024;
static constexpr int Cc = 512;
static constexpr int Dc = 256;
static constexpr int Hc = 4;
static constexpr int Sc = 1026;       // 2 + K
static constexpr int FFc = 1024;
static constexpr float EPSc = 1e-5f;
static constexpr float SCALEc = 0.125f;   // 1/sqrt(64)
static constexpr float NEG_OUT = -1.0e30f;  // finite stand-in for -inf (see R1)

typedef __attribute__((ext_vector_type(8))) short short8;
typedef __attribute__((ext_vector_type(8))) unsigned short u16x8;
typedef __attribute__((ext_vector_type(4))) float f32x4;

__device__ __forceinline__ float bf2f(unsigned short u) {
  union { float f; unsigned int i; } c; c.i = ((unsigned int)u) << 16; return c.f;
}
__device__ __forceinline__ unsigned short f2bf(float f) {
  union { float f; unsigned int i; } c; c.f = f;
  unsigned int i = c.i;
  unsigned int r = (i + 0x7fffu + ((i >> 16) & 1u)) >> 16;  // RNE
  return (unsigned short)r;
}

__device__ __forceinline__ float wave_sum(float v) {
#pragma unroll
  for (int off = 32; off > 0; off >>= 1) v += __shfl_xor(v, off, 64);
  return v;
}
__device__ __forceinline__ float wave_max(float v) {
#pragma unroll
  for (int off = 32; off > 0; off >>= 1) v = fmaxf(v, __shfl_xor(v, off, 64));
  return v;
}

__device__ __forceinline__ void async_ld16(const unsigned short* g, unsigned short* l) {
  __builtin_amdgcn_global_load_lds(
      (const __attribute__((address_space(1))) void*)g,
      (__attribute__((address_space(3))) void*)l, 16, 0, 0);
}

// Fast GELU: tanh-form, err ~1e-3 relative (below bf16 rounding).
__device__ __forceinline__ float gelu_fast(float u) {
  const float z = 1.5957691216057308f * u * (1.0f + 0.044715f * u * u);
  return u / (1.0f + __expf(-z));
}

// ---------------------------------------------------------------------------
// bf16 MFMA GEMM, BK=32, double-buffered LDS, one barrier per iter,
// XCD-aware 1D grid swizzle (R7-verified: FETCH 134->21 MB on FF1).
// NEW (R8): epilogue routed through LDS -- fragments ds_write'd as bf16 into
// a 128x128 C-tile (reusing the 32 KB staging LDS), then 8 coalesced 16 B
// stores per thread. Kills the 2x WRITE amplification from scattered 2 B
// stores (TCC read-modify-write) seen in R7.
// A: [M][Kd] bf16 (CASTA=0) or fp32 (CASTA=1, cast fused into staging).
// W: [N][Kd] bf16. EPI: 1 +extraF[n] (type-emb); 2 +bf16 extraB[orow*ldc+n]
// (residual, in-place OK); 3 fast GELU; 4 bias only. Outputs bf16.
// MAP: 1 = candidate row scatter m -> (m>>10)*1026+2+(m&1023).
// ---------------------------------------------------------------------------
template <int EPI, int MAP, int CASTA>
__global__ __launch_bounds__(256) void gemm_mfma(
    const void* __restrict__ Av, const unsigned short* __restrict__ W,
    const float* __restrict__ bias, const void* extra,
    void* Cout, int N, int Kd, int ldc, int MB, int NB) {
  __shared__ unsigned short lds[16384];  // 32 KB: staging dbuf OR C-tile
  const int xcd = blockIdx.x & 7;
  const int slot = blockIdx.x >> 3;
  const int nb = slot % NB;
  const int mb = (slot / NB) * 8 + xcd;
  if (mb >= MB) return;
  const int m0 = mb * 128;
  const int n0 = nb * 128;
  const int tid = threadIdx.x;
  const int w = tid >> 6;
  const int lane = tid & 63;

  const unsigned short* A = (const unsigned short*)Av;
  const float* Af = (const float*)Av;

  // Staging: wave w, call c (0/1) covers rows [(w*2+c)*16, +16); 4 lanes/row,
  // 16 B each. Phys chunk = lane&3; global chunk XOR (row>>1)&3.
  const int srA[2] = {(w * 2 + 0) * 16 + (lane >> 2), (w * 2 + 1) * 16 + (lane >> 2)};
  const unsigned short* pA[2];
  const unsigned short* pB[2];
#pragma unroll
  for (int c = 0; c < 2; ++c) {
    const int kc = ((lane & 3) ^ ((srA[c] >> 1) & 3)) * 8;
    if (!CASTA) pA[c] = A + (size_t)(m0 + srA[c]) * Kd + kc;
    pB[c] = W + (size_t)(n0 + srA[c]) * Kd + kc;
  }
  const int lreg0 = (w * 2 + 0) * 512;
  const int lreg1 = (w * 2 + 1) * 512;

  f32x4 zero = {0.f, 0.f, 0.f, 0.f};
  f32x4 acc[4][4];
#pragma unroll
  for (int i = 0; i < 4; ++i)
#pragma unroll
    for (int j = 0; j < 4; ++j) acc[i][j] = zero;

  const int mrow = (w & 1) * 64;
  const int nrow = (w >> 1) * 64;
  const int l15 = lane & 15;
  const int quad = lane >> 4;
  const int koff = (quad ^ ((l15 >> 1) & 3)) * 16;  // byte offset of k-chunk

  auto stage = [&](int kk, int b) {
    if (CASTA) {
      // fp32 A -> bf16 LDS: 4 x (float4 load, cvt, 8B ds_write), same swizzle.
#pragma unroll
      for (int wi = 0; wi < 4; ++wi) {
        const int g = wi * 256 + tid;     // 0..1023
        const int row = g >> 3;
        const int k4 = g & 7;
        const int phys =
            row * 32 + ((((k4 >> 1) ^ ((row >> 1) & 3))) << 3) + ((k4 & 1) << 2);
        const float4 a4 =
            *(const float4*)(Af + (size_t)(m0 + row) * Kd + kk + k4 * 4);
        ushort4 o;
        o.x = f2bf(a4.x); o.y = f2bf(a4.y); o.z = f2bf(a4.z); o.w = f2bf(a4.w);
        *(ushort4*)(&lds[b * 4096 + phys]) = o;
      }
    } else {
      async_ld16(pA[0] + kk, &lds[b * 4096 + lreg0]);
      async_ld16(pA[1] + kk, &lds[b * 4096 + lreg1]);
    }
    async_ld16(pB[0] + kk, &lds[8192 + b * 4096 + lreg0]);
    async_ld16(pB[1] + kk, &lds[8192 + b * 4096 + lreg1]);
  };

  const int niter = Kd >> 5;
  stage(0, 0);  // prologue
  for (int it = 0; it < niter; ++it) {
    const int cur = it & 1;
    __syncthreads();  // drains buf[cur] loads (in flight during prev compute)
    if (it + 1 < niter) stage((it + 1) << 5, cur ^ 1);
    const char* AsB = (const char*)&lds[cur * 4096];
    const char* WsB = (const char*)&lds[8192 + cur * 4096];
    short8 af[4], bfr[4];
#pragma unroll
    for (int i = 0; i < 4; ++i)
      af[i] = *(const short8*)(AsB + (size_t)(mrow + i * 16 + l15) * 64 + koff);
#pragma unroll
    for (int j = 0; j < 4; ++j)
      bfr[j] = *(const short8*)(WsB + (size_t)(nrow + j * 16 + l15) * 64 + koff);
#pragma unroll
    for (int i = 0; i < 4; ++i)
#pragma unroll
      for (int j = 0; j < 4; ++j)
        acc[i][j] = __builtin_amdgcn_mfma_f32_16x16x32_bf16(af[i], bfr[j],
                                                            acc[i][j], 0, 0, 0);
  }

  // ---- Epilogue via LDS C-tile + coalesced stores ----
  const float* extraF = (const float*)extra;
  const unsigned short* extraB = (const unsigned short*)extra;
  float bj[4];
#pragma unroll
  for (int j = 0; j < 4; ++j) {
    const int n = n0 + nrow + j * 16 + l15;
    bj[j] = bias[n];
    if (EPI == 1) bj[j] += extraF[n];
  }
  __syncthreads();  // all MFMA ds_reads done; LDS becomes C-tile
#pragma unroll
  for (int i = 0; i < 4; ++i) {
    const int rbase = mrow + i * 16 + quad * 4;  // local row
#pragma unroll
    for (int r = 0; r < 4; ++r) {
#pragma unroll
      for (int j = 0; j < 4; ++j) {
        float v = acc[i][j][r] + bj[j];
        if (EPI == 3) v = gelu_fast(v);
        lds[(rbase + r) * 128 + nrow + j * 16 + l15] = f2bf(v);
      }
    }
  }
  __syncthreads();
  unsigned short* outb = (unsigned short*)Cout;
#pragma unroll
  for (int c = 0; c < 8; ++c) {
    const int idx = c * 256 + tid;     // 0..2047 chunk of 8 bf16
    const int row = idx >> 4;
    const int col = (idx & 15) * 8;
    const int m = m0 + row;
    const size_t orow =
        (MAP == 1) ? ((size_t)(m >> 10) * Sc + 2 + (m & 1023)) : (size_t)m;
    const size_t go = orow * (size_t)ldc + n0 + col;
    u16x8 val = *(const u16x8*)(&lds[row * 128 + col]);
    if (EPI == 2) {
      u16x8 rv = *(const u16x8*)(extraB + go);
#pragma unroll
      for (int e = 0; e < 8; ++e) val[e] = f2bf(bf2f(val[e]) + bf2f(rv[e]));
    }
    *(u16x8*)(outb + go) = val;
  }
}

// ---------------------------------------------------------------------------
// Mega weight cast: one dispatch, 10 (src fp32, dst bf16, n4) entries.
// ---------------------------------------------------------------------------
struct CastTab {
  const float* src[10];
  unsigned short* dst[10];
  int n4[10];
};
__global__ __launch_bounds__(256) void cast_multi(CastTab t) {
  const int e = blockIdx.y;
  const int n4 = t.n4[e];
  const float4* s = (const float4*)t.src[e];
  ushort4* d = (ushort4*)t.dst[e];
  for (int i = blockIdx.x * 256 + threadIdx.x; i < n4; i += gridDim.x * 256) {
    float4 f = s[i];
    ushort4 o;
    o.x = f2bf(f.x); o.y = f2bf(f.y); o.z = f2bf(f.z); o.w = f2bf(f.w);
    d[i] = o;
  }
}

// Concatenate bq|bk|bv (fp32) per layer into qkvb [L][768].
__global__ __launch_bounds__(256) void bias_concat(const float* bq, const float* bk,
                                                   const float* bv, float* qkvb) {
  const int i = blockIdx.x * 256 + threadIdx.x;
  if (i >= 2 * 768) return;
  const int l = i / 768;
  const int j = i - l * 768;
  float v;
  if (j < 256) v = bq[l * 256 + j];
  else if (j < 512) v = bk[l * 256 + j - 256];
  else v = bv[l * 256 + j - 512];
  qkvb[i] = v;
}

// ---------------------------------------------------------------------------
// Query projection (row s=0) + dustbin token (row s=1) -> bf16 x.
// ---------------------------------------------------------------------------
__global__ __launch_bounds__(256) void embed_qd(
    const float* __restrict__ qin, const float* __restrict__ qp_w,
    const float* __restrict__ qp_b, const float* __restrict__ dustbin,
    const float* __restrict__ type_emb, unsigned short* __restrict__ x) {
  const int b = blockIdx.x;
  const int d = threadIdx.x;
  __shared__ __align__(16) float qs[512];
  qs[d] = qin[b * 512 + d];
  qs[d + 256] = qin[b * 512 + 256 + d];
  __syncthreads();
  float acc = 0.0f;
  const float* wr = qp_w + (size_t)d * 512;
#pragma unroll 4
  for (int c = 0; c < 512; c += 4) {
    float4 w4 = *(const float4*)(wr + c);
    acc = fmaf(qs[c], w4.x, acc);
    acc = fmaf(qs[c + 1], w4.y, acc);
    acc = fmaf(qs[c + 2], w4.z, acc);
    acc = fmaf(qs[c + 3], w4.w, acc);
  }
  const size_t base = (size_t)b * Sc * Dc;
  x[base + d] = f2bf(acc + qp_b[d] + type_emb[d]);
  x[base + Dc + d] = f2bf(dustbin[d] + type_emb[Dc + d]);
}

// ---------------------------------------------------------------------------
// LayerNorm: bf16 in, bf16 out. One wave per row; 4 rows/block.
// ---------------------------------------------------------------------------
__global__ __launch_bounds__(256) void ln_kernel(
    const unsigned short* __restrict__ x, const float* __restrict__ w,
    const float* __restrict__ b, unsigned short* __restrict__ y, int nrows) {
  const int wave = threadIdx.x >> 6;
  const int lane = threadIdx.x & 63;
  const int row = blockIdx.x * 4 + wave;
  if (row >= nrows) return;
  const unsigned short* xr = x + (size_t)row * Dc;
  ushort4 xv = *(const ushort4*)(xr + lane * 4);
  const float v0 = bf2f(xv.x), v1 = bf2f(xv.y), v2 = bf2f(xv.z), v3 = bf2f(xv.w);
  float s = v0 + v1 + v2 + v3;
  float sq = v0 * v0 + v1 * v1 + v2 * v2 + v3 * v3;
  s = wave_sum(s);
  sq = wave_sum(sq);
  const float mean = s * (1.0f / Dc);
  const float var = sq * (1.0f / Dc) - mean * mean;
  const float rs = rsqrtf(var + EPSc);
  float4 wv = *(const float4*)(w + lane * 4);
  float4 bv = *(const float4*)(b + lane * 4);
  ushort4 o;
  o.x = f2bf((v0 - mean) * rs * wv.x + bv.x);
  o.y = f2bf((v1 - mean) * rs * wv.y + bv.y);
  o.z = f2bf((v2 - mean) * rs * wv.z + bv.z);
  o.w = f2bf((v3 - mean) * rs * wv.w + bv.w);
  *(ushort4*)(y + (size_t)row * Dc + lane * 4) = o;
}

// ---------------------------------------------------------------------------
// Global-token attention over fused qkv [BS][768] bf16 (q|k|v). Out ao bf16.
// ---------------------------------------------------------------------------
__global__ __launch_bounds__(256) void attn_global(
    const unsigned short* __restrict__ qkv, const unsigned char* __restrict__ mask,
    unsigned short* __restrict__ ao) {
  const int b = blockIdx.x;
  const int h = blockIdx.y;
  const int tid = threadIdx.x;
  const int wv = tid >> 6;
  const int lane = tid & 63;
  __shared__ float q0s[64], q1s[64];
  __shared__ float sc0[Sc], sc1[Sc];
  __shared__ float rbuf[4][2];
  __shared__ float obuf[2][4][64];
  const size_t base = (size_t)b * Sc * 768 + h * 64;
  if (tid < 64) {
    q0s[tid] = bf2f(qkv[base + tid]);
    q1s[tid] = bf2f(qkv[base + 768 + tid]);
  }
  __syncthreads();

  float lm0 = -INFINITY, lm1 = -INFINITY;
  for (int s = tid; s < Sc; s += 256) {
    const unsigned short* kr = qkv + base + 256 + (size_t)s * 768;
    float d0 = 0.0f, d1 = 0.0f;
#pragma unroll
    for (int c = 0; c < 64; c += 8) {
      u16x8 kv = *(const u16x8*)(kr + c);
#pragma unroll
      for (int e = 0; e < 8; ++e) {
        const float kf = bf2f(kv[e]);
        d0 = fmaf(q0s[c + e], kf, d0);
        d1 = fmaf(q1s[c + e], kf, d1);
      }
    }
    const bool pad = (s >= 2) && (mask[b * Kc + (s - 2)] == 0);
    const float s0 = pad ? -INFINITY : d0 * SCALEc;
    const float s1 = pad ? -INFINITY : d1 * SCALEc;
    sc0[s] = s0; sc1[s] = s1;
    lm0 = fmaxf(lm0, s0); lm1 = fmaxf(lm1, s1);
  }
  lm0 = wave_max(lm0);
  lm1 = wave_max(lm1);
  if (lane == 0) { rbuf[wv][0] = lm0; rbuf[wv][1] = lm1; }
  __syncthreads();
  const float m0 = fmaxf(fmaxf(rbuf[0][0], rbuf[1][0]), fmaxf(rbuf[2][0], rbuf[3][0]));
  const float m1 = fmaxf(fmaxf(rbuf[0][1], rbuf[1][1]), fmaxf(rbuf[2][1], rbuf[3][1]));
  float ls0 = 0.0f, ls1 = 0.0f;
  for (int s = tid; s < Sc; s += 256) {
    const float e0 = expf(sc0[s] - m0);
    const float e1 = expf(sc1[s] - m1);
    sc0[s] = e0; sc1[s] = e1;
    ls0 += e0; ls1 += e1;
  }
  ls0 = wave_sum(ls0);
  ls1 = wave_sum(ls1);
  __syncthreads();
  if (lane == 0) { rbuf[wv][0] = ls0; rbuf[wv][1] = ls1; }
  __syncthreads();
  const float t0 = rbuf[0][0] + rbuf[1][0] + rbuf[2][0] + rbuf[3][0];
  const float t1 = rbuf[0][1] + rbuf[1][1] + rbuf[2][1] + rbuf[3][1];
  float o0 = 0.0f, o1 = 0.0f;
  for (int s = wv; s < Sc; s += 4) {
    const float vvv = bf2f(qkv[base + 512 + (size_t)s * 768 + lane]);
    o0 = fmaf(sc0[s], vvv, o0);
    o1 = fmaf(sc1[s], vvv, o1);
  }
  obuf[0][wv][lane] = o0;
  obuf[1][wv][lane] = o1;
  __syncthreads();
  if (wv == 0) {
    const float a0 = obuf[0][0][lane] + obuf[0][1][lane] + obuf[0][2][lane] + obuf[0][3][lane];
    const float a1 = obuf[1][0][lane] + obuf[1][1][lane] + obuf[1][2][lane] + obuf[1][3][lane];
    const size_t ob = ((size_t)b * Sc) * Dc + h * 64;
    ao[ob + lane] = f2bf(a0 / t0);
    ao[ob + Dc + lane] = f2bf(a1 / t1);
  }
}

// ---------------------------------------------------------------------------
// Candidate attention over fused qkv: {global0, global1, self}. Out ao bf16.
// ---------------------------------------------------------------------------
__global__ __launch_bounds__(256) void attn_cand(
    const unsigned short* __restrict__ qkv, const unsigned char* __restrict__ mask,
    unsigned short* __restrict__ ao) {
  const int bk = blockIdx.x;
  const int b = bk >> 10;
  const int kk = bk & 1023;
  const int h = threadIdx.x >> 6;
  const int lane = threadIdx.x & 63;
  const size_t rowg = (size_t)b * Sc * 768 + h * 64;
  const size_t rowc = rowg + (size_t)(2 + kk) * 768;
  const float qc = bf2f(qkv[rowc + lane]);
  float p0 = qc * bf2f(qkv[rowg + 256 + lane]);
  float p1 = qc * bf2f(qkv[rowg + 256 + 768 + lane]);
  float p2 = qc * bf2f(qkv[rowc + 256 + lane]);
#pragma unroll
  for (int off = 32; off > 0; off >>= 1) {
    p0 += __shfl_xor(p0, off, 64);
    p1 += __shfl_xor(p1, off, 64);
    p2 += __shfl_xor(p2, off, 64);
  }
  const bool pad = (mask[b * Kc + kk] == 0);
  const float s0 = p0 * SCALEc;
  const float s1 = p1 * SCALEc;
  const float s2 = pad ? -INFINITY : p2 * SCALEc;
  const float m = fmaxf(fmaxf(s0, s1), s2);
  const float e0 = expf(s0 - m);
  const float e1 = expf(s1 - m);
  const float e2 = pad ? 0.0f : expf(s2 - m);
  const float inv = 1.0f / (e0 + e1 + e2);
  const float o = (e0 * bf2f(qkv[rowg + 512 + lane]) +
                   e1 * bf2f(qkv[rowg + 512 + 768 + lane]) +
                   e2 * bf2f(qkv[rowc + 512 + lane])) * inv;
  ao[((size_t)b * Sc + 2 + kk) * Dc + h * 64 + lane] = f2bf(o);
}

// ---------------------------------------------------------------------------
// Head: LN + dot(head_w) + head_b, mask-scatter into out (B, 1025). bf16 x.
// ---------------------------------------------------------------------------
__global__ __launch_bounds__(256) void head_kernel(
    const unsigned short* __restrict__ x, const float* __restrict__ lnw,
    const float* __restrict__ lnb, const float* __restrict__ hw,
    const float* __restrict__ hb, const unsigned char* __restrict__ mask,
    float* __restrict__ out) {
  const int gw = blockIdx.x * 4 + (threadIdx.x >> 6);
  const int lane = threadIdx.x & 63;
  if (gw >= Bc * 1025) return;
  const int b = gw / 1025;
  const int j = gw - b * 1025;
  const int s = 1 + j;
  const unsigned short* xr = x + ((size_t)b * Sc + s) * Dc;
  ushort4 xv = *(const ushort4*)(xr + lane * 4);
  const float v0 = bf2f(xv.x), v1 = bf2f(xv.y), v2 = bf2f(xv.z), v3 = bf2f(xv.w);
  float su = v0 + v1 + v2 + v3;
  float sq = v0 * v0 + v1 * v1 + v2 * v2 + v3 * v3;
  su = wave_sum(su);
  sq = wave_sum(sq);
  const float mean = su * (1.0f / Dc);
  const float var = sq * (1.0f / Dc) - mean * mean;
  const float rs = rsqrtf(var + EPSc);
  float4 wv = *(const float4*)(lnw + lane * 4);
  float4 bv = *(const float4*)(lnb + lane * 4);
  float4 hv = *(const float4*)(hw + lane * 4);
  float d = ((v0 - mean) * rs * wv.x + bv.x) * hv.x +
            ((v1 - mean) * rs * wv.y + bv.y) * hv.y +
            ((v2 - mean) * rs * wv.z + bv.z) * hv.z +
            ((v3 - mean) * rs * wv.w + bv.w) * hv.w;
  d = wave_sum(d);
  if (lane == 0) {
    const float logit = d + hb[0];
    float res;
    if (j == 0) res = logit;
    else res = (mask[b * Kc + (j - 1)] != 0) ? logit : NEG_OUT;
    out[(size_t)b * 1025 + j] = res;
  }
}

// ---------------------------------------------------------------------------
extern "C" void kernel_launch(void* const* d_in, const int* in_sizes, int n_in,
                              void* d_out, int out_size, void* d_ws,
                              size_t ws_size, hipStream_t stream) {
  const float* query = (const float*)d_in[0];
  const float* cands = (const float*)d_in[1];
  const unsigned char* mask = (const unsigned char*)d_in[2];
  const float* qp_w = (const float*)d_in[3];
  const float* qp_b = (const float*)d_in[4];
  const float* cp_w = (const float*)d_in[5];
  const float* cp_b = (const float*)d_in[6];
  const float* dustbin = (const float*)d_in[7];
  const float* type_emb = (const float*)d_in[8];
  const float* ln1_w = (const float*)d_in[9];
  const float* ln1_b = (const float*)d_in[10];
  const float* ln2_w = (const float*)d_in[11];
  const float* ln2_b = (const float*)d_in[12];
  const float* Wq = (const float*)d_in[13];
  const float* bq = (const float*)d_in[14];
  const float* Wk = (const float*)d_in[15];
  const float* bk = (const float*)d_in[16];
  const float* Wv = (const float*)d_in[17];
  const float* bv = (const float*)d_in[18];
  const float* Wo = (const float*)d_in[19];
  const float* bo = (const float*)d_in[20];
  const float* f1w = (const float*)d_in[21];
  const float* f1b = (const float*)d_in[22];
  const float* f2w = (const float*)d_in[23];
  const float* f2b = (const float*)d_in[24];
  const float* hlw = (const float*)d_in[25];
  const float* hlb = (const float*)d_in[26];
  const float* hw = (const float*)d_in[27];
  const float* hb = (const float*)d_in[28];
  float* out = (float*)d_out;

  const size_t XSZ = (size_t)Bc * Sc * Dc;       // 16,809,984
  const size_t FFSZ = (size_t)Bc * Sc * FFc;     // 67,239,936 (>= BS*768)

  char* p = (char*)d_ws;
  unsigned short* x = (unsigned short*)p;   p += XSZ * 2;   // bf16 residual
  unsigned short* y = (unsigned short*)p;   p += XSZ * 2;
  unsigned short* ao = (unsigned short*)p;  p += XSZ * 2;
  unsigned short* big = (unsigned short*)p; p += FFSZ * 2;
  unsigned short* qkv = big;                // [BS][768], overlapped with ff
  unsigned short* ff = big;                 // [BS][1024]
  unsigned short* cpw_b = (unsigned short*)p;      // 256x512
  unsigned short* qkvw_b = cpw_b + 131072;          // [L][768][256]
  unsigned short* Wo_b = qkvw_b + 2 * 768 * 256;    // [L][256][256]
  unsigned short* f1_b = Wo_b + 131072;             // [L][1024][256]
  unsigned short* f2_b = f1_b + 524288;             // [L][256][1024]
  float* qkvb = (float*)(f2_b + 524288);            // [L][768]

  const int BS = Bc * Sc;  // 65664 = 513*128
  // Swizzled 1D grid size: NB * (MB rounded up to multiple of 8).
  auto sgrid = [](int MB, int NB) { return (unsigned)(NB * (((MB + 7) >> 3) << 3)); };

  // One mega-cast for all weights (10 entries).
  CastTab t;
  t.src[0] = cp_w;  t.dst[0] = cpw_b; t.n4[0] = 131072 / 4;
  t.src[1] = Wo;    t.dst[1] = Wo_b;  t.n4[1] = 131072 / 4;
  t.src[2] = f1w;   t.dst[2] = f1_b;  t.n4[2] = 524288 / 4;
  t.src[3] = f2w;   t.dst[3] = f2_b;  t.n4[3] = 524288 / 4;
  for (int l = 0; l < 2; ++l) {
    t.src[4 + l * 3 + 0] = Wq + l * 65536;
    t.src[4 + l * 3 + 1] = Wk + l * 65536;
    t.src[4 + l * 3 + 2] = Wv + l * 65536;
    t.dst[4 + l * 3 + 0] = qkvw_b + l * 196608 + 0 * 65536;
    t.dst[4 + l * 3 + 1] = qkvw_b + l * 196608 + 1 * 65536;
    t.dst[4 + l * 3 + 2] = qkvw_b + l * 196608 + 2 * 65536;
    t.n4[4 + l * 3 + 0] = 65536 / 4;
    t.n4[4 + l * 3 + 1] = 65536 / 4;
    t.n4[4 + l * 3 + 2] = 65536 / 4;
  }
  cast_multi<<<dim3(128, 10), 256, 0, stream>>>(t);
  bias_concat<<<6, 256, 0, stream>>>(bq, bk, bv, qkvb);

  // Embed: candidates (fp32, fused cast) -> x rows [2,1026); rows 0,1 direct.
  gemm_mfma<1, 1, 1><<<sgrid(512, 2), 256, 0, stream>>>(
      cands, cpw_b, cp_b, type_emb + 2 * Dc, x, Dc, Cc, Dc, 512, 2);
  embed_qd<<<Bc, 256, 0, stream>>>(query, qp_w, qp_b, dustbin, type_emb, x);

  for (int l = 0; l < 2; ++l) {
    ln_kernel<<<BS / 4, 256, 0, stream>>>(x, ln1_w + l * Dc, ln1_b + l * Dc, y, BS);
    // Fused QKV: N=768, out pitch 768.
    gemm_mfma<4, 0, 0><<<sgrid(513, 6), 256, 0, stream>>>(
        y, qkvw_b + l * 196608, qkvb + l * 768, nullptr, qkv, 768, Dc, 768, 513, 6);
    attn_global<<<dim3(Bc, Hc), 256, 0, stream>>>(qkv, mask, ao);
    attn_cand<<<Bc * Kc, 256, 0, stream>>>(qkv, mask, ao);
    gemm_mfma<2, 0, 0><<<sgrid(513, 2), 256, 0, stream>>>(
        ao, Wo_b + l * 65536, bo + l * Dc, x, x, Dc, Dc, Dc, 513, 2);
    ln_kernel<<<BS / 4, 256, 0, stream>>>(x, ln2_w + l * Dc, ln2_b + l * Dc, y, BS);
    gemm_mfma<3, 0, 0><<<sgrid(513, 8), 256, 0, stream>>>(
        y, f1_b + l * 524288 / 2, f1b + l * FFc, nullptr, ff, FFc, Dc, FFc, 513, 8);
    gemm_mfma<2, 0, 0><<<sgrid(513, 2), 256, 0, stream>>>(
        ff, f2_b + l * 524288 / 2, f2b + l * Dc, x, x, Dc, FFc, Dc, 513, 2);
  }

  head_kernel<<<(Bc * 1025 + 3) / 4, 256, 0, stream>>>(x, hlw, hlb, hw, hb, mask, out);
}